// Round 1
// baseline (443.717 us; speedup 1.0000x reference)
//
#include <hip/hip_runtime.h>
#include <hip/hip_cooperative_groups.h>
#include <math.h>

namespace cg = cooperative_groups;

// CRF mean-field, fully factorized — NO O(N^2) pass.
// Single cooperative kernel: 13 former launches -> 1 launch + 12 grid.sync().
// Bilateral kernel rank-28 Taylor basis (degree 6), separable 3-D Gaussian
// convs, 5 mean-field iterations. N = 32*16*16 = 8192, C = 4.

constexpr int   NT    = 8192;
constexpr float LOG2E = 1.4426950408889634f;
constexpr float SQL2E = 1.2011224087864498f;     // sqrt(log2 e)
constexpr float INVA  = 0.2f * SQL2E;            // spatial prescale

// W rows (NT floats each):
//   0..27  : M[ab]   28..31 unused   32..35 u1[c]   36..39 u2[c]
//   40 scale1  41 scale2  42..157 conv outputs
constexpr int R_M = 0, R_U1 = 32, R_U2 = 36, R_S1 = 40, R_S2 = 41, R_CV = 42;
constexpr int NBLK = 116;                         // 112 bilateral + 4 spatial vols
constexpr int PPB  = (NT + NBLK - 1) / NBLK;      // 71 points/block for pointwise phases

static __device__ __forceinline__ float ex2(float x) {
    return __builtin_amdgcn_exp2f(x);
}

__constant__ float INVSQF[7] = {1.f, 1.f, 0.70710678f, 0.40824829f,
                                0.20412415f, 0.09128709f, 0.03726780f};
// ab -> (a,b) enumeration: for k=0..6, a=k..0, b=k-a  (must match contract order)
__constant__ int AB_A[28] = {0, 1,0, 2,1,0, 3,2,1,0, 4,3,2,1,0,
                             5,4,3,2,1,0, 6,5,4,3,2,1,0};
__constant__ int AB_B[28] = {0, 0,1, 0,1,2, 0,1,2,3, 0,1,2,3,4,
                             0,1,2,3,4,5, 0,1,2,3,4,5,6};

// ---------------- separable 3-D Gaussian conv over one staged volume --------
// SP staged as SP[(n>>4)*17 + (n&15)]; caller stages, we sync first.
static __device__ __forceinline__ void conv3d_store(float* SP,
                                                    float* __restrict__ outp,
                                                    int tid) {
    float g32[32];
#pragma unroll
    for (int d = 0; d < 32; d++) { float t = d * INVA; g32[d] = ex2(-0.5f*t*t); }
    __syncthreads();
    // z-pass: rows (x,y) at stride 17
#pragma unroll
    for (int rr = 0; rr < 2; rr++) {
        int r = tid + rr * 256;
        float v[16], acc[16];
#pragma unroll
        for (int z = 0; z < 16; z++) { v[z] = SP[r*17 + z]; acc[z] = 0.f; }
#pragma unroll
        for (int zp = 0; zp < 16; zp++)
#pragma unroll
            for (int z = 0; z < 16; z++) {
                int d = (z > zp) ? (z - zp) : (zp - z);
                acc[z] = fmaf(g32[d], v[zp], acc[z]);
            }
#pragma unroll
        for (int z = 0; z < 16; z++) SP[r*17 + z] = acc[z];
    }
    __syncthreads();
    // y-pass: rows (x,z), stride 17 between y's
#pragma unroll
    for (int rr = 0; rr < 2; rr++) {
        int r = tid + rr * 256;
        int x = r >> 4, z = r & 15;
        int base = x * 272 + z;
        float v[16], acc[16];
#pragma unroll
        for (int y = 0; y < 16; y++) { v[y] = SP[base + y*17]; acc[y] = 0.f; }
#pragma unroll
        for (int yp = 0; yp < 16; yp++)
#pragma unroll
            for (int y = 0; y < 16; y++) {
                int d = (y > yp) ? (y - yp) : (yp - y);
                acc[y] = fmaf(g32[d], v[yp], acc[y]);
            }
#pragma unroll
        for (int y = 0; y < 16; y++) SP[base + y*17] = acc[y];
    }
    __syncthreads();
    // x-pass: rows (y,z), stride 272; write to global
    {
        int base = (tid >> 4) * 17 + (tid & 15);     // 17*y + z
        float v[32], acc[32];
#pragma unroll
        for (int xp = 0; xp < 32; xp++) { v[xp] = SP[base + xp*272]; acc[xp] = 0.f; }
#pragma unroll
        for (int xp = 0; xp < 32; xp++)
#pragma unroll
            for (int x = 0; x < 32; x++) {
                int d = (x > xp) ? (x - xp) : (xp - x);
                acc[x] = fmaf(g32[d], v[xp], acc[x]);
            }
#pragma unroll
        for (int x = 0; x < 32; x++) outp[x*256 + tid] = acc[x];
    }
}

// ----------------------------- pointwise bodies -----------------------------
static __device__ __forceinline__ void init_point(float* __restrict__ W,
                                                  const float* __restrict__ lu,
                                                  int n) {
    float rs = 0.f;
#pragma unroll
    for (int ab = 0; ab < 28; ab++)
        rs = fmaf(W[(R_M+ab)*NT + n], W[(R_CV+ab)*NT + n], rs);
    float s1 = rsqrtf(rs);
    float s2 = W[R_S2*NT + n];
    W[R_S1*NT + n] = s1;
    float l0 = lu[n], l1 = lu[NT+n], l2 = lu[2*NT+n], l3 = lu[3*NT+n];
    float mx = fmaxf(fmaxf(l0,l1), fmaxf(l2,l3));
    float q0 = __expf(l0-mx), q1 = __expf(l1-mx), q2 = __expf(l2-mx), q3 = __expf(l3-mx);
    float inv = 1.f / (q0+q1+q2+q3);
    q0*=inv; q1*=inv; q2*=inv; q3*=inv;
    W[(R_U1+0)*NT+n]=q0*s1; W[(R_U1+1)*NT+n]=q1*s1; W[(R_U1+2)*NT+n]=q2*s1; W[(R_U1+3)*NT+n]=q3*s1;
    W[(R_U2+0)*NT+n]=q0*s2; W[(R_U2+1)*NT+n]=q1*s2; W[(R_U2+2)*NT+n]=q2*s2; W[(R_U2+3)*NT+n]=q3*s2;
}

static __device__ __forceinline__ void fuse_point(float* __restrict__ W,
        const float* __restrict__ lu, const float* __restrict__ compat,
        float* __restrict__ out, int n, int last) {
    float s1 = W[R_S1*NT + n], s2 = W[R_S2*NT + n];
    float q1[4] = {0.f, 0.f, 0.f, 0.f};
#pragma unroll
    for (int ab = 0; ab < 28; ab++) {
        float m = W[(R_M+ab)*NT + n];
#pragma unroll
        for (int c = 0; c < 4; c++)
            q1[c] = fmaf(m, W[(R_CV + ab*4 + c)*NT + n], q1[c]);
    }
    float comb[4];
#pragma unroll
    for (int c = 0; c < 4; c++)
        comb[c] = s1 * q1[c] + s2 * W[(R_CV + 112 + c)*NT + n];
    float q[4];
#pragma unroll
    for (int o = 0; o < 4; o++) {
        float upd = 0.f;
#pragma unroll
        for (int c = 0; c < 4; c++) upd = fmaf(compat[o*4+c], comb[c], upd);
        q[o] = lu[o*NT+n] - upd;
    }
    float mx = fmaxf(fmaxf(q[0],q[1]), fmaxf(q[2],q[3]));
    float sum = 0.f;
#pragma unroll
    for (int c = 0; c < 4; c++) { q[c] = __expf(q[c]-mx); sum += q[c]; }
    float inv = 1.f / sum;
    if (last) {
#pragma unroll
        for (int c = 0; c < 4; c++) out[c*NT+n] = q[c] * inv;
    } else {
#pragma unroll
        for (int c = 0; c < 4; c++) {
            float qq = q[c] * inv;
            W[(R_U1+c)*NT+n] = qq*s1;
            W[(R_U2+c)*NT+n] = qq*s2;
        }
    }
}

// --------------------------- the single cooperative kernel ------------------
__global__ __launch_bounds__(256) void k_crf_all(const float* __restrict__ lu,
        const float* __restrict__ feat, const float* __restrict__ compat,
        float* __restrict__ out, float* __restrict__ W) {
    cg::grid_group grid = cg::this_grid();
    __shared__ float SP[512 * 17];
    const int bid = blockIdx.x, tid = threadIdx.x;

    // ---- phase A: blocks 0..27 build + conv their own basis row (norm pass);
    //               blocks 28..115 compute closed-form scale2.
    if (bid < 28) {
        const int a = AB_A[bid], b = AB_B[bid];
        const float ca = INVSQF[a], cb = INVSQF[b];
        for (int s = tid; s < NT; s += 256) {
            float g0 = feat[s] * 0.2f, g1 = feat[NT + s] * 0.2f;
            float eg = ex2(-0.5f * LOG2E * (g0*g0 + g1*g1));
            float pa = 1.f;
            for (int i = 0; i < a; i++) pa *= g0;   // a,b wave-uniform (blockIdx)
            float pb = 1.f;
            for (int i = 0; i < b; i++) pb *= g1;
            float v = eg * pa * ca * pb * cb;
            W[(R_M + bid)*NT + s] = v;
            SP[(s >> 4)*17 + (s & 15)] = v;
        }
        conv3d_store(SP, W + (R_CV + bid)*NT, tid);
    } else {
        const int nb = (bid - 28) * 94 + tid;       // 88 blocks x 94 >= 8192
        if (tid < 94 && nb < NT) {
            int x = nb >> 8, y = (nb >> 4) & 15, z = nb & 15;
            float Sx = 0.f, Sy = 0.f, Sz = 0.f;
            for (int j = 0; j < 32; j++) { float d = (float)(x-j)*INVA; Sx += ex2(-0.5f*d*d); }
            for (int j = 0; j < 16; j++) { float d = (float)(y-j)*INVA; Sy += ex2(-0.5f*d*d); }
            for (int j = 0; j < 16; j++) { float d = (float)(z-j)*INVA; Sz += ex2(-0.5f*d*d); }
            W[R_S2*NT + nb] = rsqrtf(Sx * Sy * Sz);
        }
    }
    grid.sync();

    // ---- init: rowsum contract -> scale1, q0, u1, u2 (spread over all blocks)
    { int n = bid * PPB + tid; if (tid < PPB && n < NT) init_point(W, lu, n); }
    grid.sync();

    // ---- 5 mean-field iterations: conv(116 vols) -> fuse -> repeat
    for (int it = 0; it < 5; ++it) {
        {
            const int idx = bid;
            if (idx < 112) {
                const float* Mr = W + (R_M + (idx >> 2))*NT;
                const float* ur = W + (R_U1 + (idx & 3))*NT;
                for (int s = tid; s < NT; s += 256)
                    SP[(s >> 4)*17 + (s & 15)] = Mr[s] * ur[s];
            } else {
                const float* ur = W + (R_U2 + (idx - 112))*NT;
                for (int s = tid; s < NT; s += 256)
                    SP[(s >> 4)*17 + (s & 15)] = ur[s];
            }
            conv3d_store(SP, W + (R_CV + idx)*NT, tid);
        }
        grid.sync();
        { int n = bid * PPB + tid; if (tid < PPB && n < NT) fuse_point(W, lu, compat, out, n, it == 4); }
        grid.sync();
    }
}

// --------------------------- fallback multi-kernel path ---------------------
__global__ __launch_bounds__(256) void k_setup(const float* __restrict__ feat,
                                               float* __restrict__ W) {
    int n = blockIdx.x * 256 + threadIdx.x;
    float g0 = feat[n] * 0.2f, g1 = feat[NT + n] * 0.2f;
    float eg = ex2(-0.5f * LOG2E * (g0*g0 + g1*g1));
    float p0[7], p1[7];
    p0[0] = 1.f; p1[0] = 1.f;
#pragma unroll
    for (int i = 1; i < 7; i++) { p0[i] = p0[i-1]*g0; p1[i] = p1[i-1]*g1; }
    int ab = 0;
#pragma unroll
    for (int k = 0; k <= 6; k++)
#pragma unroll
        for (int a = k; a >= 0; a--) {
            int b = k - a;
            W[(R_M + ab)*NT + n] = eg * p0[a]*INVSQF[a] * p1[b]*INVSQF[b];
            ab++;
        }
    int x = n >> 8, y = (n >> 4) & 15, z = n & 15;
    float Sx = 0.f, Sy = 0.f, Sz = 0.f;
    for (int j = 0; j < 32; j++) { float d = (float)(x-j)*INVA; Sx += ex2(-0.5f*d*d); }
    for (int j = 0; j < 16; j++) { float d = (float)(y-j)*INVA; Sy += ex2(-0.5f*d*d); }
    for (int j = 0; j < 16; j++) { float d = (float)(z-j)*INVA; Sz += ex2(-0.5f*d*d); }
    W[R_S2*NT + n] = rsqrtf(Sx * Sy * Sz);
}

__global__ __launch_bounds__(256) void k_conv(const float* __restrict__ W,
                                              float* __restrict__ Wout, int mode) {
    __shared__ float SP[512 * 17];
    const int idx = blockIdx.x;
    const int tid = threadIdx.x;
    if (mode == 0) {
        const float* src = W + (R_M + idx) * NT;
        for (int s = tid; s < NT; s += 256)
            SP[(s >> 4)*17 + (s & 15)] = src[s];
    } else if (idx < 112) {
        const float* Mr = W + (R_M + (idx >> 2)) * NT;
        const float* ur = W + (R_U1 + (idx & 3)) * NT;
        for (int s = tid; s < NT; s += 256)
            SP[(s >> 4)*17 + (s & 15)] = Mr[s] * ur[s];
    } else {
        const float* ur = W + (R_U2 + (idx - 112)) * NT;
        for (int s = tid; s < NT; s += 256)
            SP[(s >> 4)*17 + (s & 15)] = ur[s];
    }
    conv3d_store(SP, Wout + (R_CV + idx)*NT, tid);
}

__global__ __launch_bounds__(256) void k_init(float* __restrict__ W,
                                              const float* __restrict__ lu) {
    int n = blockIdx.x * 256 + threadIdx.x;
    init_point(W, lu, n);
}

__global__ __launch_bounds__(256) void k_fuse(float* __restrict__ W,
        const float* __restrict__ lu, const float* __restrict__ compat,
        float* __restrict__ out, int last) {
    int n = blockIdx.x * 256 + threadIdx.x;
    fuse_point(W, lu, compat, out, n, last);
}

// ---------------------------------------------------------------- driver
extern "C" void kernel_launch(void* const* d_in, const int* in_sizes, int n_in,
                              void* d_out, int out_size, void* d_ws, size_t ws_size,
                              hipStream_t stream) {
    const float* lu     = (const float*)d_in[0];
    const float* feat   = (const float*)d_in[1];
    const float* compat = (const float*)d_in[2];
    float* out = (float*)d_out;
    float* W   = (float*)d_ws;     // needs 158*NT*4 = 5.2 MB

    void* args[] = {(void*)&lu, (void*)&feat, (void*)&compat, (void*)&out, (void*)&W};
    hipError_t rc = hipLaunchCooperativeKernel((const void*)k_crf_all,
                                               dim3(NBLK), dim3(256), args, 0, stream);
    if (rc != hipSuccess) {
        (void)hipGetLastError();   // clear, fall back to multi-launch path
        k_setup<<<dim3(32), dim3(256), 0, stream>>>(feat, W);
        k_conv <<<dim3(28), dim3(256), 0, stream>>>(W, W, 0);
        k_init <<<dim3(32), dim3(256), 0, stream>>>(W, lu);
        for (int it = 0; it < 5; it++) {
            k_conv<<<dim3(116), dim3(256), 0, stream>>>(W, W, 1);
            k_fuse<<<dim3(32),  dim3(256), 0, stream>>>(W, lu, compat, out, it == 4);
        }
    }
}